// Round 7
// baseline (192.833 us; speedup 1.0000x reference)
//
#include <hip/hip_runtime.h>
#include <hip/hip_bf16.h>
#include <math.h>

// Problem constants (CrossAttention_14955076125227)
//   B=4, N=2048, M=2048, Dq=512, Dc=768, H=8, Dh=64, inner=512
#define BB 4
#define NN 2048
#define MM 2048
#define DQ 512
#define DC 768
#define NH 8
#define DH 64
#define INNER 512
#define KVS 1024   // fused K|V row stride (bf16 elems)

typedef short bf16x8 __attribute__((ext_vector_type(8)));
typedef short bf16x4 __attribute__((ext_vector_type(4)));
typedef float f32x4  __attribute__((ext_vector_type(4)));

__device__ inline short fbf(float f) {
    __hip_bfloat16 h = __float2bfloat16(f);
    return __builtin_bit_cast(short, h);
}
__device__ inline float bf2f(short s) {
    unsigned u = (unsigned)(unsigned short)s;
    return __builtin_bit_cast(float, u << 16);
}

// raw v_exp_f32 (2^x): 1 VALU instr. Inputs here are bounded (|x| < ~40), so
// the ocml range/NaN fixup path (~12 instrs) is dead weight.
__device__ inline float fexp2(float x) {
    float r;
    asm("v_exp_f32 %0, %1" : "=v"(r) : "v"(x));
    return r;
}

// async global->LDS, 16 B per lane. LDS dest is wave-uniform base; HW adds lane*16.
__device__ inline void gld16(const void* gptr, void* lds_uniform_base) {
    __builtin_amdgcn_global_load_lds(
        (const __attribute__((address_space(1))) void*)gptr,
        (__attribute__((address_space(3))) void*)lds_uniform_base, 16, 0, 0);
}

// ---------------------------------------------------------------------------
// Fused prep kernel: LN(x), LN(cond) -> bf16 (one WAVE per row, no barriers),
// and all 4 weight transposes.
// grid: 5376 blocks x 256 thr.
// ---------------------------------------------------------------------------
__global__ __launch_bounds__(256) void prep_k(
    const float* __restrict__ x, const float* __restrict__ cond,
    const float* __restrict__ gx, const float* __restrict__ bx_,
    const float* __restrict__ gc, const float* __restrict__ bc,
    short* __restrict__ xn, short* __restrict__ cn,
    const float* __restrict__ Wq, const float* __restrict__ Wk,
    const float* __restrict__ Wv, const float* __restrict__ Wo,
    short* __restrict__ Wqt, short* __restrict__ Wkvt, short* __restrict__ Wot)
{
    const int bxid = blockIdx.x;
    const int t = threadIdx.x;

    if (bxid < 4096) {   // ---- LayerNorm path: one wave per row ----
        const int which = bxid >> 11;            // 0: x, 1: cond
        const int wave = t >> 6, lane = t & 63;
        const int row = (bxid & 2047) * 4 + wave;
        const float* in = which ? cond : x;
        const float* g  = which ? gc : gx;
        const float* bb = which ? bc : bx_;
        short* out      = which ? cn : xn;
        const int D     = which ? DC : DQ;
        const int nk    = which ? 3 : 2;         // 256-float chunks

        const float* xr = in + (size_t)row * D;
        float v[12];
        float s = 0.f, s2 = 0.f;
        #pragma unroll
        for (int k = 0; k < 3; ++k) {
            if (k < nk) {
                float4 f = *(const float4*)&xr[lane * 4 + k * 256];
                v[k * 4 + 0] = f.x; v[k * 4 + 1] = f.y;
                v[k * 4 + 2] = f.z; v[k * 4 + 3] = f.w;
                s  += f.x + f.y + f.z + f.w;
                s2 += f.x * f.x + f.y * f.y + f.z * f.z + f.w * f.w;
            }
        }
        #pragma unroll
        for (int off = 32; off; off >>= 1) {
            s  += __shfl_xor(s,  off, 64);
            s2 += __shfl_xor(s2, off, 64);
        }
        const float mu = s / (float)D;
        const float rstd = rsqrtf(s2 / (float)D - mu * mu + 1e-5f);
        short* o = out + (size_t)row * D;
        #pragma unroll
        for (int k = 0; k < 3; ++k) {
            if (k < nk) {
                const int d = lane * 4 + k * 256;
                float4 gg = *(const float4*)&g[d];
                float4 bv = *(const float4*)&bb[d];
                short4 sv;
                sv.x = fbf((v[k * 4 + 0] - mu) * rstd * gg.x + bv.x);
                sv.y = fbf((v[k * 4 + 1] - mu) * rstd * gg.y + bv.y);
                sv.z = fbf((v[k * 4 + 2] - mu) * rstd * gg.z + bv.z);
                sv.w = fbf((v[k * 4 + 3] - mu) * rstd * gg.w + bv.w);
                *(short4*)&o[d] = sv;
            }
        }
    } else {              // ---- weight transpose path ----
        const int tb = bxid - 4096;
        const int y = tb >> 4;
        const int n0 = (tb & 15) * 32;
        const float* W; short* Wt; int K, k0;
        if (y < 16)      { W = Wq; Wt = Wqt;  K = DQ; k0 = y * 32; }
        else if (y < 40) { W = Wk; Wt = Wkvt; K = DC; k0 = (y - 16) * 32; }
        else if (y < 64) { W = Wv; Wt = Wkvt + (size_t)512 * DC; K = DC; k0 = (y - 40) * 32; }
        else             { W = Wo; Wt = Wot;  K = DQ; k0 = (y - 64) * 32; }

        __shared__ float tile[32][33];
        const int r = t >> 3, c4 = (t & 7) * 4;
        float4 vv = *(const float4*)&W[(size_t)(k0 + r) * 512 + n0 + c4];
        tile[c4 + 0][r] = vv.x; tile[c4 + 1][r] = vv.y;
        tile[c4 + 2][r] = vv.z; tile[c4 + 3][r] = vv.w;
        __syncthreads();
        short4 sv;
        sv.x = fbf(tile[r][c4 + 0]); sv.y = fbf(tile[r][c4 + 1]);
        sv.z = fbf(tile[r][c4 + 2]); sv.w = fbf(tile[r][c4 + 3]);
        *(short4*)&Wt[(size_t)(n0 + r) * K + k0 + c4] = sv;
    }
}

// ---------------------------------------------------------------------------
// Final LayerNorm with fused residual: out = LN(bf16(ob) + x), D=512.
// One wave per row, 4 rows per block, no barriers / LDS.
// ---------------------------------------------------------------------------
__global__ __launch_bounds__(256) void layernorm_res_f32(
    const short* __restrict__ ob, const float* __restrict__ x,
    const float* __restrict__ g, const float* __restrict__ b,
    float* __restrict__ out)
{
    const int wave = threadIdx.x >> 6, lane = threadIdx.x & 63;
    const int row = blockIdx.x * 4 + wave;
    const size_t base = (size_t)row * DQ;
    float v[8];
    float s = 0.f, s2 = 0.f;
    #pragma unroll
    for (int k = 0; k < 2; ++k) {
        const int d = lane * 4 + k * 256;
        short4 ov = *(const short4*)&ob[base + d];
        float4 xv = *(const float4*)&x[base + d];
        float a0 = bf2f(ov.x) + xv.x, a1 = bf2f(ov.y) + xv.y;
        float a2 = bf2f(ov.z) + xv.z, a3 = bf2f(ov.w) + xv.w;
        v[k * 4 + 0] = a0; v[k * 4 + 1] = a1; v[k * 4 + 2] = a2; v[k * 4 + 3] = a3;
        s  += a0 + a1 + a2 + a3;
        s2 += a0 * a0 + a1 * a1 + a2 * a2 + a3 * a3;
    }
    #pragma unroll
    for (int off = 32; off; off >>= 1) {
        s  += __shfl_xor(s,  off, 64);
        s2 += __shfl_xor(s2, off, 64);
    }
    const float mu = s / (float)DQ;
    const float rstd = rsqrtf(s2 / (float)DQ - mu * mu + 1e-5f);
    #pragma unroll
    for (int k = 0; k < 2; ++k) {
        const int d = lane * 4 + k * 256;
        float4 gv = *(const float4*)&g[d];
        float4 bv = *(const float4*)&b[d];
        float4 r;
        r.x = (v[k * 4 + 0] - mu) * rstd * gv.x + bv.x;
        r.y = (v[k * 4 + 1] - mu) * rstd * gv.y + bv.y;
        r.z = (v[k * 4 + 2] - mu) * rstd * gv.z + bv.z;
        r.w = (v[k * 4 + 3] - mu) * rstd * gv.w + bv.w;
        *(float4*)&out[base + d] = r;
    }
}

// ---------------------------------------------------------------------------
// Fused q+kv projection GEMM, GBK=64 serial K-loop, NOW 512 THREADS (8 waves,
// 4x2 wave grid, 32x64 per wave): grid stays 768 = 3 blocks/CU but
// waves/SIMD 3 -> 6, so co-resident blocks fill each other's barrier drains.
// XOR chunk-swizzle unchanged (source-swizzled global + swizzled read).
// launch_bounds (512,6): VGPR <= 85 (acc 32 + frags + addr fits).
// grid (12, 64): x<4: q=(xn@Wq)*qsc (K=512); x>=4: kv=cn@[Wk|Wv] (K=768).
// ---------------------------------------------------------------------------
#define GBK 64

__global__ __launch_bounds__(512, 6) void qkv_gemm(
    const short* __restrict__ xn, const short* __restrict__ cn,
    const short* __restrict__ Wqt, const short* __restrict__ Wkvt,
    short* __restrict__ qb, short* __restrict__ kvb, float qsc)
{
    const short* A; const short* Bt; short* outp; int K, Nout, n0; float sc;
    if (blockIdx.x < 4) {
        A = xn; Bt = Wqt; outp = qb; K = DQ; Nout = 512;
        n0 = blockIdx.x * 128; sc = qsc;
    } else {
        A = cn; Bt = Wkvt; outp = kvb; K = DC; Nout = 1024;
        n0 = (blockIdx.x - 4) * 128; sc = 1.f;
    }
    __shared__ short As[128 * GBK];   // 16 KB, row-major [128][64], chunk-swizzled
    __shared__ short Bs[128 * GBK];   // 16 KB
    const int t = threadIdx.x;
    const int w = t >> 6, lane = t & 63;
    const int quad = lane >> 4, l16 = lane & 15;
    const int rsw = l16 & 7;          // read-side XOR key (row&7 == l16&7)
    const int m0 = blockIdx.y * 128;
    const int wm = (w >> 1) * 32, wn = (w & 1) * 64;   // 32x64 per wave

    f32x4 acc[2][4];
    #pragma unroll
    for (int i = 0; i < 2; ++i)
        #pragma unroll
        for (int j = 0; j < 4; ++j) acc[i][j] = (f32x4){0.f, 0.f, 0.f, 0.f};

    // staging: 16 x 1KB issues per matrix; wave w does issues w*2, w*2+1.
    // chunk c: row = c>>3, stored col-chunk = c&7 holds global chunk
    // (c&7)^(row&7)  (inverse of read-side XOR).
    for (int kt = 0; kt < K; kt += GBK) {
        __syncthreads();
        #pragma unroll
        for (int i = 0; i < 2; ++i) {
            const int j = w * 2 + i;
            const int c = j * 64 + lane;
            const int row = c >> 3, col = (c & 7) ^ (row & 7);
            gld16(&A[(size_t)(m0 + row) * K + kt + col * 8],
                  (char*)As + j * 1024);
            gld16(&Bt[(size_t)(n0 + row) * K + kt + col * 8],
                  (char*)Bs + j * 1024);
        }
        __syncthreads();

        #pragma unroll
        for (int kk = 0; kk < 2; ++kk) {
            bf16x8 af[2], bfr[4];
            #pragma unroll
            for (int mt = 0; mt < 2; ++mt)
                af[mt] = *(const bf16x8*)((const char*)As
                    + (wm + mt * 16 + l16) * 128 + (((kk << 2) | quad) ^ rsw) * 16);
            #pragma unroll
            for (int nt = 0; nt < 4; ++nt)
                bfr[nt] = *(const bf16x8*)((const char*)Bs
                    + (wn + nt * 16 + l16) * 128 + (((kk << 2) | quad) ^ rsw) * 16);
            #pragma unroll
            for (int mt = 0; mt < 2; ++mt)
                #pragma unroll
                for (int nt = 0; nt < 4; ++nt)
                    acc[mt][nt] = __builtin_amdgcn_mfma_f32_16x16x32_bf16(
                        af[mt], bfr[nt], acc[mt][nt], 0, 0, 0);
        }
    }

    #pragma unroll
    for (int mt = 0; mt < 2; ++mt)
        #pragma unroll
        for (int r = 0; r < 4; ++r) {
            const int m = m0 + wm + mt * 16 + quad * 4 + r;
            #pragma unroll
            for (int nt = 0; nt < 4; ++nt) {
                const int n = n0 + wn + nt * 16 + l16;
                outp[(size_t)m * Nout + n] = fbf(acc[mt][nt][r] * sc);
            }
        }
}

// ---------------------------------------------------------------------------
// o-proj GEMM: C = ab @ Wot^T + bias, bf16 out. Tile 128x64, GBK=64,
// NOW 512 THREADS (8 waves, 4x2, 32x32 per wave) + DOUBLE-BUFFER (48 KB LDS
// is free: occupancy is grid-capped at 2 blocks/CU). One barrier per K-step,
// prefetch in flight during compute. waves/SIMD 2 -> 4.
// ---------------------------------------------------------------------------
__global__ __launch_bounds__(512, 4) void oproj_gemm(
    const short* __restrict__ A, const short* __restrict__ Bt,
    short* __restrict__ outb, const float* __restrict__ bias)
{
    const int K = INNER, Nout = INNER;
    __shared__ short As[2][128 * GBK];   // 2 x 16 KB
    __shared__ short Bs[2][64 * GBK];    // 2 x  8 KB
    const int t = threadIdx.x;
    const int w = t >> 6, lane = t & 63;
    const int quad = lane >> 4, l16 = lane & 15;
    const int rsw = l16 & 7;
    const int m0 = blockIdx.y * 128, n0 = blockIdx.x * 64;
    const int wm = (w >> 1) * 32, wn = (w & 1) * 32;   // 32x32 per wave

    f32x4 acc[2][2];
    #pragma unroll
    for (int i = 0; i < 2; ++i)
        #pragma unroll
        for (int j = 0; j < 2; ++j) acc[i][j] = (f32x4){0.f, 0.f, 0.f, 0.f};

    auto stage = [&](int buf, int kt) {
        #pragma unroll
        for (int i = 0; i < 2; ++i) {          // A: 16 chunks, 2 per wave
            const int j = w * 2 + i;
            const int c = j * 64 + lane;
            const int row = c >> 3, col = (c & 7) ^ (row & 7);
            gld16(&A[(size_t)(m0 + row) * K + kt + col * 8],
                  (char*)As[buf] + j * 1024);
        }
        {                                       // B: 8 chunks, 1 per wave
            const int c = w * 64 + lane;
            const int row = c >> 3, col = (c & 7) ^ (row & 7);
            gld16(&Bt[(size_t)(n0 + row) * K + kt + col * 8],
                  (char*)Bs[buf] + w * 1024);
        }
    };
    auto compute = [&](int buf) {
        #pragma unroll
        for (int kk = 0; kk < 2; ++kk) {
            bf16x8 af[2], bfr[2];
            #pragma unroll
            for (int mt = 0; mt < 2; ++mt)
                af[mt] = *(const bf16x8*)((const char*)As[buf]
                    + (wm + mt * 16 + l16) * 128 + (((kk << 2) | quad) ^ rsw) * 16);
            #pragma unroll
            for (int nt = 0; nt < 2; ++nt)
                bfr[nt] = *(const bf16x8*)((const char*)Bs[buf]
                    + (wn + nt * 16 + l16) * 128 + (((kk << 2) | quad) ^ rsw) * 16);
            #pragma unroll
            for (int mt = 0; mt < 2; ++mt)
                #pragma unroll
                for (int nt = 0; nt < 2; ++nt)
                    acc[mt][nt] = __builtin_amdgcn_mfma_f32_16x16x32_bf16(
                        af[mt], bfr[nt], acc[mt][nt], 0, 0, 0);
        }
    };

    stage(0, 0);
    __syncthreads();
    int cur = 0;
    for (int kt = 0; kt < K; kt += GBK) {
        if (kt + GBK < K) stage(cur ^ 1, kt + GBK);   // prefetch in flight
        compute(cur);
        __syncthreads();                               // drains vmcnt + WAR
        cur ^= 1;
    }

    #pragma unroll
    for (int mt = 0; mt < 2; ++mt)
        #pragma unroll
        for (int r = 0; r < 4; ++r) {
            const int m = m0 + wm + mt * 16 + quad * 4 + r;
            #pragma unroll
            for (int nt = 0; nt < 2; ++nt) {
                const int n = n0 + wn + nt * 16 + l16;
                outb[(size_t)m * Nout + n] = fbf(acc[mt][nt][r] + bias[n]);
            }
        }
}

// ---------------------------------------------------------------------------
// bf16-MFMA flash attention v10 (unchanged):
//  * raw v_exp_f32, s_setprio around MFMA clusters
//  * QT=128, JT=64, dbuf 64KB, gld_lds staging, XOR-swizzled K, tr_b16 V
// ---------------------------------------------------------------------------
#define QT 128
#define JT 64
#define MH (MM / 2)      // 1024 j's per wave-half
#define NIT (MH / JT)    // 16
#define ABUF 32768       // bytes per K|V buffer (2 halves x (8KB K + 8KB V))

__global__ __launch_bounds__(512, 4) void attention_mfma(
    const short* __restrict__ q, const short* __restrict__ kv,
    short* __restrict__ o)
{
    // bijective XCD swizzle: nwg=512, 64 per XCD; 2 (b,h) per XCD.
    const int bid = blockIdx.x;
    const int wg  = (bid & 7) * 64 + (bid >> 3);
    const int ib  = wg & 15;           // i-block within (b,h)
    const int bh  = wg >> 4;
    const int h   = bh & 7, b = bh >> 3;
    const int i0  = ib * QT;

    const int t = threadIdx.x;
    const int lane = t & 63;
    const int wave = t >> 6;
    const int w4 = wave & 3, hh = wave >> 2;   // row-group / j-half
    const int quad = lane >> 4, l16 = lane & 15;

    __shared__ __align__(16) char smem[2 * ABUF];

    // ---- Q fragments (B operand of S^T = K Q^T), 2 i-tiles per wave ----
    bf16x8 qf[2][2];
    #pragma unroll
    for (int it = 0; it < 2; ++it) {
        const int qrow = i0 + w4 * 32 + it * 16 + l16;
        const short* qp = &q[((size_t)(b * NN + qrow)) * INNER + h * DH];
        qf[it][0] = *(const bf16x8*)&qp[quad * 8];
        qf[it][1] = *(const bf16x8*)&qp[32 + quad * 8];
    }

    f32x4 Oa[2][4];           // [it][dt]
    f32x4 La[2];
    #pragma unroll
    for (int it = 0; it < 2; ++it) {
        La[it] = (f32x4){0.f, 0.f, 0.f, 0.f};
        #pragma unroll
        for (int dt = 0; dt < 4; ++dt) Oa[it][dt] = (f32x4){0.f, 0.f, 0.f, 0.f};
    }

    const bf16x8 ones8 = {(short)0x3F80, (short)0x3F80, (short)0x3F80, (short)0x3F80,
                          (short)0x3F80, (short)0x3F80, (short)0x3F80, (short)0x3F80};

    // ---- staging source addresses (global_load_lds, 16B/lane, 4/wave) ----
    const int kr = w4 * 16 + (lane >> 3);
    const int kc = ((lane & 7) ^ (lane >> 3)) * 8;
    const short* kp = kv + ((size_t)(b * MM + hh * MH + kr)) * KVS + h * DH + kc;
    const int vj = (lane >> 3) * 4 + ((lane & 7) >> 1);
    const int vd = w4 * 16 + (lane & 1) * 8;
    const short* vp = kv + ((size_t)(b * MM + hh * MH + vj)) * KVS + 512 + h * DH + vd;
    const size_t ADV = (size_t)JT * KVS;

    char* const kdst = smem + hh * 8192 + w4 * 2048;            // buf0 K dest
    char* const vdst = smem + 16384 + hh * 8192 + w4 * 2048;    // buf0 V dest

    // ---- compute-side LDS addressing ----
    const char* const Kh0 = smem + hh * 8192;
    const int koff0 = l16 * 128 + ((quad ^ (l16 & 7)) * 16);    // chain0 chunk
    const unsigned vbase =
        (unsigned)(size_t)(__attribute__((address_space(3))) char*)(smem + 16384 + hh * 8192)
        + (unsigned)(lane * 8);

    auto stage = [&](int pb) {
        gld16(kp,            kdst + pb);
        gld16(kp + 8 * KVS,  kdst + pb + 1024);
        gld16(vp,            vdst + pb);
        gld16(vp + 32 * KVS, vdst + pb + 1024);
        kp += ADV; vp += ADV;
    };

    auto compute = [&](int pb) {
        const char* Kh = Kh0 + pb;
        #pragma unroll
        for (int cc = 0; cc < 2; ++cc) {
            const int kb = cc * 4096 + koff0;
            bf16x8 kf0 = *(const bf16x8*)(Kh + kb);
            bf16x8 kf1 = *(const bf16x8*)(Kh + (kb ^ 64));
            bf16x8 kg0 = *(const bf16x8*)(Kh + kb + 2048);
            bf16x8 kg1 = *(const bf16x8*)(Kh + ((kb + 2048) ^ 64));

            f32x4 S00 = (f32x4){0.f, 0.f, 0.f, 0.f};
            f32x4 S01 = (f32x4){0.f, 0.f, 0.f, 0.f};
            f32x4 S10 = (f32x4){0.f, 0.f, 0.f, 0.f};
            f32x4 S11 = (f32x4){0.f, 0.f, 0.f, 0.f};
            __builtin_amdgcn_s_setprio(1);
            S00 = __builtin_amdgcn_mfma_f32_16x16x32_bf16(kf0, qf[0][0], S00, 0, 0, 0);
            S00 = __builtin_amdgcn_mfma_f32_16x16x32_bf16(kf1, qf[0][1], S00, 0, 0, 0);
            S01 = __builtin_amdgcn_mfma_f32_16x16x32_bf16(kf0, qf[1][0], S01, 0, 0, 0);
            S01 = __builtin_amdgcn_mfma_f32_16x16x32_bf16(kf1, qf[1][1], S01, 0, 0, 0);
            S10 = __builtin_amdgcn_mfma_f32_16x16x32_bf16(kg0, qf[0][0], S10, 0, 0, 0);
            S10 = __builtin_amdgcn_mfma_f32_16x16x32_bf16(kg1, qf[0][1], S10, 0, 0, 0);
            S11 = __builtin_amdgcn_mfma_f32_16x16x32_bf16(kg0, qf[1][0], S11, 0, 0, 0);
            S11 = __builtin_amdgcn_mfma_f32_16x16x32_bf16(kg1, qf[1][1], S11, 0, 0, 0);
            __builtin_amdgcn_s_setprio(0);

            // issue V transpose-reads early; consumed after softmax VALU work
            bf16x4 ta0, tb0, ta1, tb1, ta2, tb2, ta3, tb3;
            {
                const unsigned va = vbase + (unsigned)(cc * 1024 + pb);
                asm volatile(
                    "ds_read_b64_tr_b16 %0, %8 offset:0\n\t"
                    "ds_read_b64_tr_b16 %1, %8 offset:512\n\t"
                    "ds_read_b64_tr_b16 %2, %8 offset:2048\n\t"
                    "ds_read_b64_tr_b16 %3, %8 offset:2560\n\t"
                    "ds_read_b64_tr_b16 %4, %8 offset:4096\n\t"
                    "ds_read_b64_tr_b16 %5, %8 offset:4608\n\t"
                    "ds_read_b64_tr_b16 %6, %8 offset:6144\n\t"
                    "ds_read_b64_tr_b16 %7, %8 offset:6656"
                    : "=&v"(ta0), "=&v"(tb0), "=&v"(ta1), "=&v"(tb1),
                      "=&v"(ta2), "=&v"(tb2), "=&v"(ta3), "=&v"(tb3)
                    : "v"(va));
            }

            // p = exp2(s); pack into A-frag k-slot order {S0*[0..3], S1*[0..3]}
            bf16x8 p8[2];
            {
                const float e0 = fexp2(S00[0]), e1 = fexp2(S00[1]);
                const float e2 = fexp2(S00[2]), e3 = fexp2(S00[3]);
                const float f0 = fexp2(S10[0]), f1 = fexp2(S10[1]);
                const float f2 = fexp2(S10[2]), f3 = fexp2(S10[3]);
                uint4 pk;
                pk.x = __builtin_amdgcn_perm(__builtin_bit_cast(unsigned, e1),
                                             __builtin_bit_cast(unsigned, e0), 0x07060302u);
                pk.y = __builtin_amdgcn_perm(__builtin_bit_cast(unsigned, e3),
                                             __builtin_bit_cast(unsigned, e2), 0x07060302u);
                pk.z = __builtin_amdgcn_perm(__builtin_bit_cast(unsigned, f1),
                                             __builtin_bit_cast(unsigned, f0), 0x07060302u);
                pk.w = __builtin_amdgcn_perm(__builtin_bit_cast(unsigned, f3),
                                             __builtin_bit_cast(unsigned, f2), 0x07060302u);
                p8[0] = __builtin_bit_cast(bf16x8, pk);
            }
            {
                const float e0 = fexp2(S01[0]), e1 = fexp2(S01[1]);
                const float e2 = fexp2(S01[2]), e3 = fexp2(S01[3]);
                const float f0 = fexp2(S11[0]), f1 = fexp2(S11[1]);
                const float f2 = fexp2(S11[2]), f3 = fexp2(S11[3]);
                uint4 pk;
                pk.x = __builtin_amdgcn_perm(__builtin_bit_cast(unsigned, e1),
                                             __builtin_bit_cast(unsigned, e0), 0x07060302u);
                pk.y = __builtin_amdgcn_perm(__builtin_bit_cast(unsigned, e3),
                                             __builtin_bit_cast(unsigned, e2), 0x07060302u);
                pk.z = __builtin_amdgcn_perm(__builtin_bit_cast(unsigned, f1),
                                             __builtin_bit_cast(unsigned, f0), 0x07060302u);
                pk.w = __builtin_amdgcn_perm(__builtin_bit_cast(unsigned, f3),
                                             __builtin_bit_cast(unsigned, f2), 0x07060302u);
                p8[1] = __builtin_bit_cast(bf16x8, pk);
            }

            asm volatile("s_waitcnt lgkmcnt(0)" ::: "memory");
            __builtin_amdgcn_sched_barrier(0);

            const bf16x8 v0 = __builtin_shufflevector(ta0, tb0, 0, 1, 2, 3, 4, 5, 6, 7);
            const bf16x8 v1 = __builtin_shufflevector(ta1, tb1, 0, 1, 2, 3, 4, 5, 6, 7);
            const bf16x8 v2 = __builtin_shufflevector(ta2, tb2, 0, 1, 2, 3, 4, 5, 6, 7);
            const bf16x8 v3 = __builtin_shufflevector(ta3, tb3, 0, 1, 2, 3, 4, 5, 6, 7);
            __builtin_amdgcn_s_setprio(1);
            Oa[0][0] = __builtin_amdgcn_mfma_f32_16x16x32_bf16(p8[0], v0, Oa[0][0], 0, 0, 0);
            Oa[0][1] = __builtin_amdgcn_mfma_f32_16x16x32_bf16(p8[0], v1, Oa[0][1], 0, 0, 0);
            Oa[0][2] = __builtin_amdgcn_mfma_f32_16x16x32_bf16(p8[0], v2, Oa[0][2], 0, 0, 0);
            Oa[0][3] = __builtin_amdgcn_mfma_f32_16x16x32_bf16(p8[0], v3, Oa[0][3], 0, 0, 0);
            Oa[1][0] = __builtin_amdgcn_mfma_f32_16x16x32_bf16(p8[1], v0, Oa[1][0], 0, 0, 0);
            Oa[1][1] = __builtin_amdgcn_mfma_f32_16x16x32_bf16(p8[1], v1, Oa[1][1], 0, 0, 0);
            Oa[1][2] = __builtin_amdgcn_mfma_f32_16x16x32_bf16(p8[1], v2, Oa[1][2], 0, 0, 0);
            Oa[1][3] = __builtin_amdgcn_mfma_f32_16x16x32_bf16(p8[1], v3, Oa[1][3], 0, 0, 0);
            La[0]    = __builtin_amdgcn_mfma_f32_16x16x32_bf16(p8[0], ones8, La[0], 0, 0, 0);
            La[1]    = __builtin_amdgcn_mfma_f32_16x16x32_bf16(p8[1], ones8, La[1], 0, 0, 0);
            __builtin_amdgcn_s_setprio(0);
        }
    };

    // prologue: stage iter 0 into buf0 (__syncthreads drains vmcnt)
    stage(0);
    __syncthreads();

    for (int itr = 0; itr < NIT; itr += 2) {
        stage(ABUF);                         // prefetch itr+1 -> buf1
        compute(0);
        __syncthreads();
        if (itr + 2 < NIT) stage(0);         // prefetch itr+2 -> buf0
        compute(ABUF);
        __syncthreads();
    }

    // ---- combine the two j-halves (O, l additive) via LDS overlay ----
    float (*Obuf)[32][68] = (float (*)[32][68])smem;           // 34816 B
    float (*Lbuf)[32]     = (float (*)[32])(smem + 34816);     //   512 B
    if (hh == 1) {
        #pragma unroll
        for (int it = 0; it < 2; ++it) {
            #pragma unroll
            for (int r = 0; r < 4; ++r) {
                const int qr = it * 16 + quad * 4 + r;
                #pragma unroll
                for (int dt = 0; dt < 4; ++dt)
                    Obuf[w4][qr][dt * 16 + l16] = Oa[it][dt][r];
                if (l16 == 0) Lbuf[w4][qr] = La[it][r];
            }
        }
    }
    __syncthreads();
    if (hh == 0) {
        #pragma unroll
        for (int it = 0; it < 2; ++it) {
            #pragma unroll
            for (int r = 0; r < 4; ++r) {
                const int qr = it * 16 + quad * 4 + r;
                const float ltot = La[it][r] + Lbuf[w4][qr];  // same across l16
                const float inv = 1.f / ltot;
                const int row = i0 + w4 * 32 + qr;
                #pragma unroll
                for (int dt = 0; dt < 4; ++dt) {
                    const float val = Oa[it][dt][r] + Obuf[w4][qr][dt * 16 + l16];
                    o[((size_t)(b * NN + row)) * INNER + h * DH + dt * 16 + l16] =
                        fbf(val * inv);
                }
            }
        }
    }
}

// ---------------------------------------------------------------------------
// Launch
// ---------------------------------------------------------------------------
extern "C" void kernel_launch(void* const* d_in, const int* in_sizes, int n_in,
                              void* d_out, int out_size, void* d_ws, size_t ws_size,
                              hipStream_t stream)
{
    const float* x     = (const float*)d_in[0];
    const float* cond  = (const float*)d_in[1];
    const float* lnx_g = (const float*)d_in[2];
    const float* lnx_b = (const float*)d_in[3];
    const float* lnc_g = (const float*)d_in[4];
    const float* lnc_b = (const float*)d_in[5];
    const float* Wq    = (const float*)d_in[6];
    const float* Wk    = (const float*)d_in[7];
    const float* Wv    = (const float*)d_in[8];
    const float* Wo    = (const float*)d_in[9];
    const float* bo    = (const float*)d_in[10];
    const float* lnf_g = (const float*)d_in[11];
    const float* lnf_b = (const float*)d_in[12];
    float* out = (float*)d_out;
    char* ws = (char*)d_ws;

    const int R = BB * NN;  // 8192

    // workspace layout (bytes, 16B-aligned)
    short* xn_bf  = (short*)(ws);                    //  8 MB
    short* cn_bf  = (short*)(ws + (8u << 20));       // 12 MB
    short* Wq_t   = (short*)(ws + (20u << 20));      // 0.5 MB
    short* Wo_t   = (short*)(ws + (21u << 20));      // 0.5 MB
    short* Wkv_t  = (short*)(ws + (22u << 20));      // 1.5 MB
    short* qb     = (short*)(ws + (24u << 20));      //  8 MB
    short* kvb    = (short*)(ws + (32u << 20));      // 16 MB
    short* ab     = (short*)(ws + (48u << 20));      //  8 MB
    short* ob     = (short*)(ws + (56u << 20));      //  8 MB

    // fused LN(x)+LN(cond)+all weight transposes (one launch)
    prep_k<<<5376, 256, 0, stream>>>(
        x, cond, lnx_g, lnx_b, lnc_g, lnc_b, xn_bf, cn_bf,
        Wq, Wk, Wv, Wo, Wq_t, Wkv_t, Wo_t);

    // q = (xn @ Wq)*0.125*log2e ; [k|v] = cn @ [Wk|Wv]
    qkv_gemm<<<dim3(12, R / 128), 512, 0, stream>>>(
        xn_bf, cn_bf, Wq_t, Wkv_t, qb, kvb, 0.125f * 1.44269504089f);

    attention_mfma<<<dim3(BB * NH * (NN / QT)), 512, 0, stream>>>(qb, kvb, ab);

    // o-proj: bf16 out + bias (residual folded into the final LN)
    oproj_gemm<<<dim3(INNER / 64, R / 128), 512, 0, stream>>>(ab, Wo_t, ob, bo);

    layernorm_res_f32<<<R / 4, 256, 0, stream>>>(ob, x, lnf_g, lnf_b, out);
}

// Round 8
// 188.211 us; speedup vs baseline: 1.0246x; 1.0246x over previous
//
#include <hip/hip_runtime.h>
#include <hip/hip_bf16.h>
#include <math.h>

// Problem constants (CrossAttention_14955076125227)
//   B=4, N=2048, M=2048, Dq=512, Dc=768, H=8, Dh=64, inner=512
#define BB 4
#define NN 2048
#define MM 2048
#define DQ 512
#define DC 768
#define NH 8
#define DH 64
#define INNER 512
#define KVS 1024   // fused K|V row stride (bf16 elems)

typedef short bf16x8 __attribute__((ext_vector_type(8)));
typedef short bf16x4 __attribute__((ext_vector_type(4)));
typedef float f32x4  __attribute__((ext_vector_type(4)));

__device__ inline short fbf(float f) {
    __hip_bfloat16 h = __float2bfloat16(f);
    return __builtin_bit_cast(short, h);
}
__device__ inline float bf2f(short s) {
    unsigned u = (unsigned)(unsigned short)s;
    return __builtin_bit_cast(float, u << 16);
}

// raw v_exp_f32 (2^x): 1 VALU instr. Inputs here are bounded (|x| < ~40), so
// the ocml range/NaN fixup path (~12 instrs) is dead weight.
__device__ inline float fexp2(float x) {
    float r;
    asm("v_exp_f32 %0, %1" : "=v"(r) : "v"(x));
    return r;
}

// async global->LDS, 16 B per lane. LDS dest is wave-uniform base; HW adds lane*16.
__device__ inline void gld16(const void* gptr, void* lds_uniform_base) {
    __builtin_amdgcn_global_load_lds(
        (const __attribute__((address_space(1))) void*)gptr,
        (__attribute__((address_space(3))) void*)lds_uniform_base, 16, 0, 0);
}

// ---------------------------------------------------------------------------
// Fused prep kernel: LN(x), LN(cond) -> bf16 (one WAVE per row, no barriers),
// and all 4 weight transposes.
// grid: 5376 blocks x 256 thr.
// ---------------------------------------------------------------------------
__global__ __launch_bounds__(256) void prep_k(
    const float* __restrict__ x, const float* __restrict__ cond,
    const float* __restrict__ gx, const float* __restrict__ bx_,
    const float* __restrict__ gc, const float* __restrict__ bc,
    short* __restrict__ xn, short* __restrict__ cn,
    const float* __restrict__ Wq, const float* __restrict__ Wk,
    const float* __restrict__ Wv, const float* __restrict__ Wo,
    short* __restrict__ Wqt, short* __restrict__ Wkvt, short* __restrict__ Wot)
{
    const int bxid = blockIdx.x;
    const int t = threadIdx.x;

    if (bxid < 4096) {   // ---- LayerNorm path: one wave per row ----
        const int which = bxid >> 11;            // 0: x, 1: cond
        const int wave = t >> 6, lane = t & 63;
        const int row = (bxid & 2047) * 4 + wave;
        const float* in = which ? cond : x;
        const float* g  = which ? gc : gx;
        const float* bb = which ? bc : bx_;
        short* out      = which ? cn : xn;
        const int D     = which ? DC : DQ;
        const int nk    = which ? 3 : 2;         // 256-float chunks

        const float* xr = in + (size_t)row * D;
        float v[12];
        float s = 0.f, s2 = 0.f;
        #pragma unroll
        for (int k = 0; k < 3; ++k) {
            if (k < nk) {
                float4 f = *(const float4*)&xr[lane * 4 + k * 256];
                v[k * 4 + 0] = f.x; v[k * 4 + 1] = f.y;
                v[k * 4 + 2] = f.z; v[k * 4 + 3] = f.w;
                s  += f.x + f.y + f.z + f.w;
                s2 += f.x * f.x + f.y * f.y + f.z * f.z + f.w * f.w;
            }
        }
        #pragma unroll
        for (int off = 32; off; off >>= 1) {
            s  += __shfl_xor(s,  off, 64);
            s2 += __shfl_xor(s2, off, 64);
        }
        const float mu = s / (float)D;
        const float rstd = rsqrtf(s2 / (float)D - mu * mu + 1e-5f);
        short* o = out + (size_t)row * D;
        #pragma unroll
        for (int k = 0; k < 3; ++k) {
            if (k < nk) {
                const int d = lane * 4 + k * 256;
                float4 gg = *(const float4*)&g[d];
                float4 bv = *(const float4*)&bb[d];
                short4 sv;
                sv.x = fbf((v[k * 4 + 0] - mu) * rstd * gg.x + bv.x);
                sv.y = fbf((v[k * 4 + 1] - mu) * rstd * gg.y + bv.y);
                sv.z = fbf((v[k * 4 + 2] - mu) * rstd * gg.z + bv.z);
                sv.w = fbf((v[k * 4 + 3] - mu) * rstd * gg.w + bv.w);
                *(short4*)&o[d] = sv;
            }
        }
    } else {              // ---- weight transpose path ----
        const int tb = bxid - 4096;
        const int y = tb >> 4;
        const int n0 = (tb & 15) * 32;
        const float* W; short* Wt; int K, k0;
        if (y < 16)      { W = Wq; Wt = Wqt;  K = DQ; k0 = y * 32; }
        else if (y < 40) { W = Wk; Wt = Wkvt; K = DC; k0 = (y - 16) * 32; }
        else if (y < 64) { W = Wv; Wt = Wkvt + (size_t)512 * DC; K = DC; k0 = (y - 40) * 32; }
        else             { W = Wo; Wt = Wot;  K = DQ; k0 = (y - 64) * 32; }

        __shared__ float tile[32][33];
        const int r = t >> 3, c4 = (t & 7) * 4;
        float4 vv = *(const float4*)&W[(size_t)(k0 + r) * 512 + n0 + c4];
        tile[c4 + 0][r] = vv.x; tile[c4 + 1][r] = vv.y;
        tile[c4 + 2][r] = vv.z; tile[c4 + 3][r] = vv.w;
        __syncthreads();
        short4 sv;
        sv.x = fbf(tile[r][c4 + 0]); sv.y = fbf(tile[r][c4 + 1]);
        sv.z = fbf(tile[r][c4 + 2]); sv.w = fbf(tile[r][c4 + 3]);
        *(short4*)&Wt[(size_t)(n0 + r) * K + k0 + c4] = sv;
    }
}

// ---------------------------------------------------------------------------
// Final LayerNorm with fused residual: out = LN(bf16(ob) + x), D=512.
// One wave per row, 4 rows per block, no barriers / LDS.
// ---------------------------------------------------------------------------
__global__ __launch_bounds__(256) void layernorm_res_f32(
    const short* __restrict__ ob, const float* __restrict__ x,
    const float* __restrict__ g, const float* __restrict__ b,
    float* __restrict__ out)
{
    const int wave = threadIdx.x >> 6, lane = threadIdx.x & 63;
    const int row = blockIdx.x * 4 + wave;
    const size_t base = (size_t)row * DQ;
    float v[8];
    float s = 0.f, s2 = 0.f;
    #pragma unroll
    for (int k = 0; k < 2; ++k) {
        const int d = lane * 4 + k * 256;
        short4 ov = *(const short4*)&ob[base + d];
        float4 xv = *(const float4*)&x[base + d];
        float a0 = bf2f(ov.x) + xv.x, a1 = bf2f(ov.y) + xv.y;
        float a2 = bf2f(ov.z) + xv.z, a3 = bf2f(ov.w) + xv.w;
        v[k * 4 + 0] = a0; v[k * 4 + 1] = a1; v[k * 4 + 2] = a2; v[k * 4 + 3] = a3;
        s  += a0 + a1 + a2 + a3;
        s2 += a0 * a0 + a1 * a1 + a2 * a2 + a3 * a3;
    }
    #pragma unroll
    for (int off = 32; off; off >>= 1) {
        s  += __shfl_xor(s,  off, 64);
        s2 += __shfl_xor(s2, off, 64);
    }
    const float mu = s / (float)DQ;
    const float rstd = rsqrtf(s2 / (float)DQ - mu * mu + 1e-5f);
    #pragma unroll
    for (int k = 0; k < 2; ++k) {
        const int d = lane * 4 + k * 256;
        float4 gv = *(const float4*)&g[d];
        float4 bv = *(const float4*)&b[d];
        float4 r;
        r.x = (v[k * 4 + 0] - mu) * rstd * gv.x + bv.x;
        r.y = (v[k * 4 + 1] - mu) * rstd * gv.y + bv.y;
        r.z = (v[k * 4 + 2] - mu) * rstd * gv.z + bv.z;
        r.w = (v[k * 4 + 3] - mu) * rstd * gv.w + bv.w;
        *(float4*)&out[base + d] = r;
    }
}

// ---------------------------------------------------------------------------
// Fused q+kv projection GEMM, GBK=64 serial K-loop (round-4/6 structure:
// highest-occupancy implicit overlap beat explicit dbuf). 32 MFMA per
// barrier-pair; XOR chunk-swizzle (source-swizzled global + swizzled read).
// launch_bounds (256,4). grid (12, 64):
//  x<4 : q = (xn @ Wq)*qsc (K=512); x>=4: kv = cn @ [Wk|Wv] (K=768).
// ---------------------------------------------------------------------------
#define GBK 64

__global__ __launch_bounds__(256, 4) void qkv_gemm(
    const short* __restrict__ xn, const short* __restrict__ cn,
    const short* __restrict__ Wqt, const short* __restrict__ Wkvt,
    short* __restrict__ qb, short* __restrict__ kvb, float qsc)
{
    const short* A; const short* Bt; short* outp; int K, Nout, n0; float sc;
    if (blockIdx.x < 4) {
        A = xn; Bt = Wqt; outp = qb; K = DQ; Nout = 512;
        n0 = blockIdx.x * 128; sc = qsc;
    } else {
        A = cn; Bt = Wkvt; outp = kvb; K = DC; Nout = 1024;
        n0 = (blockIdx.x - 4) * 128; sc = 1.f;
    }
    __shared__ short As[128 * GBK];   // 16 KB, row-major [128][64], chunk-swizzled
    __shared__ short Bs[128 * GBK];   // 16 KB
    const int t = threadIdx.x;
    const int w = t >> 6, lane = t & 63;
    const int quad = lane >> 4, l16 = lane & 15;
    const int rsw = l16 & 7;          // read-side XOR key (row&7 == l16&7)
    const int m0 = blockIdx.y * 128;
    const int wm = (w >> 1) * 64, wn = (w & 1) * 64;

    f32x4 acc[4][4];
    #pragma unroll
    for (int i = 0; i < 4; ++i)
        #pragma unroll
        for (int j = 0; j < 4; ++j) acc[i][j] = (f32x4){0.f, 0.f, 0.f, 0.f};

    // staging: 16 x 1KB issues per matrix; wave w does issues w*4..w*4+3.
    // chunk c: row = c>>3, stored col-chunk = c&7 holds global chunk
    // (c&7)^(row&7)  (inverse of read-side XOR).
    const int c_  = w * 4 * 64 + lane;   // base chunk id for i=0

    for (int kt = 0; kt < K; kt += GBK) {
        __syncthreads();
        #pragma unroll
        for (int i = 0; i < 4; ++i) {
            const int c = c_ + i * 64;
            const int row = c >> 3, col = (c & 7) ^ (row & 7);
            gld16(&A[(size_t)(m0 + row) * K + kt + col * 8],
                  (char*)As + (w * 4 + i) * 1024);
            gld16(&Bt[(size_t)(n0 + row) * K + kt + col * 8],
                  (char*)Bs + (w * 4 + i) * 1024);
        }
        __syncthreads();

        #pragma unroll
        for (int kk = 0; kk < 2; ++kk) {
            bf16x8 af[4], bfr[4];
            #pragma unroll
            for (int mt = 0; mt < 4; ++mt)
                af[mt] = *(const bf16x8*)((const char*)As
                    + (wm + mt * 16 + l16) * 128 + (((kk << 2) | quad) ^ rsw) * 16);
            #pragma unroll
            for (int nt = 0; nt < 4; ++nt)
                bfr[nt] = *(const bf16x8*)((const char*)Bs
                    + (wn + nt * 16 + l16) * 128 + (((kk << 2) | quad) ^ rsw) * 16);
            #pragma unroll
            for (int mt = 0; mt < 4; ++mt)
                #pragma unroll
                for (int nt = 0; nt < 4; ++nt)
                    acc[mt][nt] = __builtin_amdgcn_mfma_f32_16x16x32_bf16(
                        af[mt], bfr[nt], acc[mt][nt], 0, 0, 0);
        }
    }

    #pragma unroll
    for (int mt = 0; mt < 4; ++mt)
        #pragma unroll
        for (int r = 0; r < 4; ++r) {
            const int m = m0 + wm + mt * 16 + quad * 4 + r;
            #pragma unroll
            for (int nt = 0; nt < 4; ++nt) {
                const int n = n0 + wn + nt * 16 + l16;
                outp[(size_t)m * Nout + n] = fbf(acc[mt][nt][r] * sc);
            }
        }
}

// ---------------------------------------------------------------------------
// o-proj GEMM: C = ab @ Wot^T + bias, bf16 out. Tile 128x64, GBK=64 serial,
// XOR chunk-swizzled LDS. launch_bounds (256,4).
// ---------------------------------------------------------------------------
__global__ __launch_bounds__(256, 4) void oproj_gemm(
    const short* __restrict__ A, const short* __restrict__ Bt,
    short* __restrict__ outb, const float* __restrict__ bias)
{
    const int K = INNER, Nout = INNER;
    __shared__ short As[128 * GBK];   // 16 KB
    __shared__ short Bs[64 * GBK];    //  8 KB
    const int t = threadIdx.x;
    const int w = t >> 6, lane = t & 63;
    const int quad = lane >> 4, l16 = lane & 15;
    const int rsw = l16 & 7;
    const int m0 = blockIdx.y * 128, n0 = blockIdx.x * 64;
    const int wm = (w >> 1) * 64, wn = (w & 1) * 32;

    f32x4 acc[4][2];
    #pragma unroll
    for (int i = 0; i < 4; ++i)
        #pragma unroll
        for (int j = 0; j < 2; ++j) acc[i][j] = (f32x4){0.f, 0.f, 0.f, 0.f};

    for (int kt = 0; kt < K; kt += GBK) {
        __syncthreads();
        #pragma unroll
        for (int i = 0; i < 4; ++i) {
            const int c = (w * 4 + i) * 64 + lane;
            const int row = c >> 3, col = (c & 7) ^ (row & 7);
            gld16(&A[(size_t)(m0 + row) * K + kt + col * 8],
                  (char*)As + (w * 4 + i) * 1024);
        }
        #pragma unroll
        for (int i = 0; i < 2; ++i) {
            const int c = (w * 2 + i) * 64 + lane;
            const int row = c >> 3, col = (c & 7) ^ (row & 7);
            gld16(&Bt[(size_t)(n0 + row) * K + kt + col * 8],
                  (char*)Bs + (w * 2 + i) * 1024);
        }
        __syncthreads();

        #pragma unroll
        for (int kk = 0; kk < 2; ++kk) {
            bf16x8 af[4], bfr[2];
            #pragma unroll
            for (int mt = 0; mt < 4; ++mt)
                af[mt] = *(const bf16x8*)((const char*)As
                    + (wm + mt * 16 + l16) * 128 + (((kk << 2) | quad) ^ rsw) * 16);
            #pragma unroll
            for (int nt = 0; nt < 2; ++nt)
                bfr[nt] = *(const bf16x8*)((const char*)Bs
                    + (wn + nt * 16 + l16) * 128 + (((kk << 2) | quad) ^ rsw) * 16);
            #pragma unroll
            for (int mt = 0; mt < 4; ++mt)
                #pragma unroll
                for (int nt = 0; nt < 2; ++nt)
                    acc[mt][nt] = __builtin_amdgcn_mfma_f32_16x16x32_bf16(
                        af[mt], bfr[nt], acc[mt][nt], 0, 0, 0);
        }
    }

    #pragma unroll
    for (int mt = 0; mt < 4; ++mt)
        #pragma unroll
        for (int r = 0; r < 4; ++r) {
            const int m = m0 + wm + mt * 16 + quad * 4 + r;
            #pragma unroll
            for (int nt = 0; nt < 2; ++nt) {
                const int n = n0 + wn + nt * 16 + l16;
                outb[(size_t)m * Nout + n] = fbf(acc[mt][nt][r] + bias[n]);
            }
        }
}

// ---------------------------------------------------------------------------
// bf16-MFMA flash attention v10 (unchanged):
//  * raw v_exp_f32, s_setprio around MFMA clusters
//  * QT=128, JT=64, dbuf 64KB, gld_lds staging, XOR-swizzled K, tr_b16 V
// ---------------------------------------------------------------------------
#define QT 128
#define JT 64
#define MH (MM / 2)      // 1024 j's per wave-half
#define NIT (MH / JT)    // 16
#define ABUF 32768       // bytes per K|V buffer (2 halves x (8KB K + 8KB V))

__global__ __launch_bounds__(512, 4) void attention_mfma(
    const short* __restrict__ q, const short* __restrict__ kv,
    short* __restrict__ o)
{
    // bijective XCD swizzle: nwg=512, 64 per XCD; 2 (b,h) per XCD.
    const int bid = blockIdx.x;
    const int wg  = (bid & 7) * 64 + (bid >> 3);
    const int ib  = wg & 15;           // i-block within (b,h)
    const int bh  = wg >> 4;
    const int h   = bh & 7, b = bh >> 3;
    const int i0  = ib * QT;

    const int t = threadIdx.x;
    const int lane = t & 63;
    const int wave = t >> 6;
    const int w4 = wave & 3, hh = wave >> 2;   // row-group / j-half
    const int quad = lane >> 4, l16 = lane & 15;

    __shared__ __align__(16) char smem[2 * ABUF];

    // ---- Q fragments (B operand of S^T = K Q^T), 2 i-tiles per wave ----
    bf16x8 qf[2][2];
    #pragma unroll
    for (int it = 0; it < 2; ++it) {
        const int qrow = i0 + w4 * 32 + it * 16 + l16;
        const short* qp = &q[((size_t)(b * NN + qrow)) * INNER + h * DH];
        qf[it][0] = *(const bf16x8*)&qp[quad * 8];
        qf[it][1] = *(const bf16x8*)&qp[32 + quad * 8];
    }

    f32x4 Oa[2][4];           // [it][dt]
    f32x4 La[2];
    #pragma unroll
    for (int it = 0; it < 2; ++it) {
        La[it] = (f32x4){0.f, 0.f, 0.f, 0.f};
        #pragma unroll
        for (int dt = 0; dt < 4; ++dt) Oa[it][dt] = (f32x4){0.f, 0.f, 0.f, 0.f};
    }

    const bf16x8 ones8 = {(short)0x3F80, (short)0x3F80, (short)0x3F80, (short)0x3F80,
                          (short)0x3F80, (short)0x3F80, (short)0x3F80, (short)0x3F80};

    // ---- staging source addresses (global_load_lds, 16B/lane, 4/wave) ----
    const int kr = w4 * 16 + (lane >> 3);
    const int kc = ((lane & 7) ^ (lane >> 3)) * 8;
    const short* kp = kv + ((size_t)(b * MM + hh * MH + kr)) * KVS + h * DH + kc;
    const int vj = (lane >> 3) * 4 + ((lane & 7) >> 1);
    const int vd = w4 * 16 + (lane & 1) * 8;
    const short* vp = kv + ((size_t)(b * MM + hh * MH + vj)) * KVS + 512 + h * DH + vd;
    const size_t ADV = (size_t)JT * KVS;

    char* const kdst = smem + hh * 8192 + w4 * 2048;            // buf0 K dest
    char* const vdst = smem + 16384 + hh * 8192 + w4 * 2048;    // buf0 V dest

    // ---- compute-side LDS addressing ----
    const char* const Kh0 = smem + hh * 8192;
    const int koff0 = l16 * 128 + ((quad ^ (l16 & 7)) * 16);    // chain0 chunk
    const unsigned vbase =
        (unsigned)(size_t)(__attribute__((address_space(3))) char*)(smem + 16384 + hh * 8192)
        + (unsigned)(lane * 8);

    auto stage = [&](int pb) {
        gld16(kp,            kdst + pb);
        gld16(kp + 8 * KVS,  kdst + pb + 1024);
        gld16(vp,            vdst + pb);
        gld16(vp + 32 * KVS, vdst + pb + 1024);
        kp += ADV; vp += ADV;
    };

    auto compute = [&](int pb) {
        const char* Kh = Kh0 + pb;
        #pragma unroll
        for (int cc = 0; cc < 2; ++cc) {
            const int kb = cc * 4096 + koff0;
            bf16x8 kf0 = *(const bf16x8*)(Kh + kb);
            bf16x8 kf1 = *(const bf16x8*)(Kh + (kb ^ 64));
            bf16x8 kg0 = *(const bf16x8*)(Kh + kb + 2048);
            bf16x8 kg1 = *(const bf16x8*)(Kh + ((kb + 2048) ^ 64));

            f32x4 S00 = (f32x4){0.f, 0.f, 0.f, 0.f};
            f32x4 S01 = (f32x4){0.f, 0.f, 0.f, 0.f};
            f32x4 S10 = (f32x4){0.f, 0.f, 0.f, 0.f};
            f32x4 S11 = (f32x4){0.f, 0.f, 0.f, 0.f};
            __builtin_amdgcn_s_setprio(1);
            S00 = __builtin_amdgcn_mfma_f32_16x16x32_bf16(kf0, qf[0][0], S00, 0, 0, 0);
            S00 = __builtin_amdgcn_mfma_f32_16x16x32_bf16(kf1, qf[0][1], S00, 0, 0, 0);
            S01 = __builtin_amdgcn_mfma_f32_16x16x32_bf16(kf0, qf[1][0], S01, 0, 0, 0);
            S01 = __builtin_amdgcn_mfma_f32_16x16x32_bf16(kf1, qf[1][1], S01, 0, 0, 0);
            S10 = __builtin_amdgcn_mfma_f32_16x16x32_bf16(kg0, qf[0][0], S10, 0, 0, 0);
            S10 = __builtin_amdgcn_mfma_f32_16x16x32_bf16(kg1, qf[0][1], S10, 0, 0, 0);
            S11 = __builtin_amdgcn_mfma_f32_16x16x32_bf16(kg0, qf[1][0], S11, 0, 0, 0);
            S11 = __builtin_amdgcn_mfma_f32_16x16x32_bf16(kg1, qf[1][1], S11, 0, 0, 0);
            __builtin_amdgcn_s_setprio(0);

            // issue V transpose-reads early; consumed after softmax VALU work
            bf16x4 ta0, tb0, ta1, tb1, ta2, tb2, ta3, tb3;
            {
                const unsigned va = vbase + (unsigned)(cc * 1024 + pb);
                asm volatile(
                    "ds_read_b64_tr_b16 %0, %8 offset:0\n\t"
                    "ds_read_b64_tr_b16 %1, %8 offset:512\n\t"
                    "ds_read_b64_tr_b16 %2, %8 offset:2048\n\t"
                    "ds_read_b64_tr_b16 %3, %8 offset:2560\n\t"
                    "ds_read_b64_tr_b16 %4, %8 offset:4096\n\t"
                    "ds_read_b64_tr_b16 %5, %8 offset:4608\n\t"
                    "ds_read_b64_tr_b16 %6, %8 offset:6144\n\t"
                    "ds_read_b64_tr_b16 %7, %8 offset:6656"
                    : "=&v"(ta0), "=&v"(tb0), "=&v"(ta1), "=&v"(tb1),
                      "=&v"(ta2), "=&v"(tb2), "=&v"(ta3), "=&v"(tb3)
                    : "v"(va));
            }

            // p = exp2(s); pack into A-frag k-slot order {S0*[0..3], S1*[0..3]}
            bf16x8 p8[2];
            {
                const float e0 = fexp2(S00[0]), e1 = fexp2(S00[1]);
                const float e2 = fexp2(S00[2]), e3 = fexp2(S00[3]);
                const float f0 = fexp2(S10[0]), f1 = fexp2(S10[1]);
                const float f2 = fexp2(S10[2]), f3 = fexp2(S10[3]);
                uint4 pk;
                pk.x = __builtin_amdgcn_perm(__builtin_bit_cast(unsigned, e1),
                                             __builtin_bit_cast(unsigned, e0), 0x07060302u);
                pk.y = __builtin_amdgcn_perm(__builtin_bit_cast(unsigned, e3),
                                             __builtin_bit_cast(unsigned, e2), 0x07060302u);
                pk.z = __builtin_amdgcn_perm(__builtin_bit_cast(unsigned, f1),
                                             __builtin_bit_cast(unsigned, f0), 0x07060302u);
                pk.w = __builtin_amdgcn_perm(__builtin_bit_cast(unsigned, f3),
                                             __builtin_bit_cast(unsigned, f2), 0x07060302u);
                p8[0] = __builtin_bit_cast(bf16x8, pk);
            }
            {
                const float e0 = fexp2(S01[0]), e1 = fexp2(S01[1]);
                const float e2 = fexp2(S01[2]), e3 = fexp2(S01[3]);
                const float f0 = fexp2(S11[0]), f1 = fexp2(S11[1]);
                const float f2 = fexp2(S11[2]), f3 = fexp2(S11[3]);
                uint4 pk;
                pk.x = __builtin_amdgcn_perm(__builtin_bit_cast(unsigned, e1),
                                             __builtin_bit_cast(unsigned, e0), 0x07060302u);
                pk.y = __builtin_amdgcn_perm(__builtin_bit_cast(unsigned, e3),
                                             __builtin_bit_cast(unsigned, e2), 0x07060302u);
                pk.z = __builtin_amdgcn_perm(__builtin_bit_cast(unsigned, f1),
                                             __builtin_bit_cast(unsigned, f0), 0x07060302u);
                pk.w = __builtin_amdgcn_perm(__builtin_bit_cast(unsigned, f3),
                                             __builtin_bit_cast(unsigned, f2), 0x07060302u);
                p8[1] = __builtin_bit_cast(bf16x8, pk);
            }

            asm volatile("s_waitcnt lgkmcnt(0)" ::: "memory");
            __builtin_amdgcn_sched_barrier(0);

            const bf16x8 v0 = __builtin_shufflevector(ta0, tb0, 0, 1, 2, 3, 4, 5, 6, 7);
            const bf16x8 v1 = __builtin_shufflevector(ta1, tb1, 0, 1, 2, 3, 4, 5, 6, 7);
            const bf16x8 v2 = __builtin_shufflevector(ta2, tb2, 0, 1, 2, 3, 4, 5, 6, 7);
            const bf16x8 v3 = __builtin_shufflevector(ta3, tb3, 0, 1, 2, 3, 4, 5, 6, 7);
            __builtin_amdgcn_s_setprio(1);
            Oa[0][0] = __builtin_amdgcn_mfma_f32_16x16x32_bf16(p8[0], v0, Oa[0][0], 0, 0, 0);
            Oa[0][1] = __builtin_amdgcn_mfma_f32_16x16x32_bf16(p8[0], v1, Oa[0][1], 0, 0, 0);
            Oa[0][2] = __builtin_amdgcn_mfma_f32_16x16x32_bf16(p8[0], v2, Oa[0][2], 0, 0, 0);
            Oa[0][3] = __builtin_amdgcn_mfma_f32_16x16x32_bf16(p8[0], v3, Oa[0][3], 0, 0, 0);
            Oa[1][0] = __builtin_amdgcn_mfma_f32_16x16x32_bf16(p8[1], v0, Oa[1][0], 0, 0, 0);
            Oa[1][1] = __builtin_amdgcn_mfma_f32_16x16x32_bf16(p8[1], v1, Oa[1][1], 0, 0, 0);
            Oa[1][2] = __builtin_amdgcn_mfma_f32_16x16x32_bf16(p8[1], v2, Oa[1][2], 0, 0, 0);
            Oa[1][3] = __builtin_amdgcn_mfma_f32_16x16x32_bf16(p8[1], v3, Oa[1][3], 0, 0, 0);
            La[0]    = __builtin_amdgcn_mfma_f32_16x16x32_bf16(p8[0], ones8, La[0], 0, 0, 0);
            La[1]    = __builtin_amdgcn_mfma_f32_16x16x32_bf16(p8[1], ones8, La[1], 0, 0, 0);
            __builtin_amdgcn_s_setprio(0);
        }
    };

    // prologue: stage iter 0 into buf0 (__syncthreads drains vmcnt)
    stage(0);
    __syncthreads();

    for (int itr = 0; itr < NIT; itr += 2) {
        stage(ABUF);                         // prefetch itr+1 -> buf1
        compute(0);
        __syncthreads();
        if (itr + 2 < NIT) stage(0);         // prefetch itr+2 -> buf0
        compute(ABUF);
        __syncthreads();
    }

    // ---- combine the two j-halves (O, l additive) via LDS overlay ----
    float (*Obuf)[32][68] = (float (*)[32][68])smem;           // 34816 B
    float (*Lbuf)[32]     = (float (*)[32])(smem + 34816);     //   512 B
    if (hh == 1) {
        #pragma unroll
        for (int it = 0; it < 2; ++it) {
            #pragma unroll
            for (int r = 0; r < 4; ++r) {
                const int qr = it * 16 + quad * 4 + r;
                #pragma unroll
                for (int dt = 0; dt < 4; ++dt)
                    Obuf[w4][qr][dt * 16 + l16] = Oa[it][dt][r];
                if (l16 == 0) Lbuf[w4][qr] = La[it][r];
            }
        }
    }
    __syncthreads();
    if (hh == 0) {
        #pragma unroll
        for (int it = 0; it < 2; ++it) {
            #pragma unroll
            for (int r = 0; r < 4; ++r) {
                const int qr = it * 16 + quad * 4 + r;
                const float ltot = La[it][r] + Lbuf[w4][qr];  // same across l16
                const float inv = 1.f / ltot;
                const int row = i0 + w4 * 32 + qr;
                #pragma unroll
                for (int dt = 0; dt < 4; ++dt) {
                    const float val = Oa[it][dt][r] + Obuf[w4][qr][dt * 16 + l16];
                    o[((size_t)(b * NN + row)) * INNER + h * DH + dt * 16 + l16] =
                        fbf(val * inv);
                }
            }
        }
    }
}

// ---------------------------------------------------------------------------
// Launch
// ---------------------------------------------------------------------------
extern "C" void kernel_launch(void* const* d_in, const int* in_sizes, int n_in,
                              void* d_out, int out_size, void* d_ws, size_t ws_size,
                              hipStream_t stream)
{
    const float* x     = (const float*)d_in[0];
    const float* cond  = (const float*)d_in[1];
    const float* lnx_g = (const float*)d_in[2];
    const float* lnx_b = (const float*)d_in[3];
    const float* lnc_g = (const float*)d_in[4];
    const float* lnc_b = (const float*)d_in[5];
    const float* Wq    = (const float*)d_in[6];
    const float* Wk    = (const float*)d_in[7];
    const float* Wv    = (const float*)d_in[8];
    const float* Wo    = (const float*)d_in[9];
    const float* bo    = (const float*)d_in[10];
    const float* lnf_g = (const float*)d_in[11];
    const float* lnf_b = (const float*)d_in[12];
    float* out = (float*)d_out;
    char* ws = (char*)d_ws;

    const int R = BB * NN;  // 8192

    // workspace layout (bytes, 16B-aligned)
    short* xn_bf  = (short*)(ws);                    //  8 MB
    short* cn_bf  = (short*)(ws + (8u << 20));       // 12 MB
    short* Wq_t   = (short*)(ws + (20u << 20));      // 0.5 MB
    short* Wo_t   = (short*)(ws + (21u << 20));      // 0.5 MB
    short* Wkv_t  = (short*)(ws + (22u << 20));      // 1.5 MB
    short* qb     = (short*)(ws + (24u << 20));      //  8 MB
    short* kvb    = (short*)(ws + (32u << 20));      // 16 MB
    short* ab     = (short*)(ws + (48u << 20));      //  8 MB
    short* ob     = (short*)(ws + (56u << 20));      //  8 MB

    // fused LN(x)+LN(cond)+all weight transposes (one launch)
    prep_k<<<5376, 256, 0, stream>>>(
        x, cond, lnx_g, lnx_b, lnc_g, lnc_b, xn_bf, cn_bf,
        Wq, Wk, Wv, Wo, Wq_t, Wkv_t, Wo_t);

    // q = (xn @ Wq)*0.125*log2e ; [k|v] = cn @ [Wk|Wv]
    qkv_gemm<<<dim3(12, R / 128), 256, 0, stream>>>(
        xn_bf, cn_bf, Wq_t, Wkv_t, qb, kvb, 0.125f * 1.44269504089f);

    attention_mfma<<<dim3(BB * NH * (NN / QT)), 512, 0, stream>>>(qb, kvb, ab);

    // o-proj: bf16 out + bias (residual folded into the final LN)
    oproj_gemm<<<dim3(INNER / 64, R / 128), 256, 0, stream>>>(ab, Wo_t, ob, bo);

    layernorm_res_f32<<<R / 4, 256, 0, stream>>>(ob, x, lnf_g, lnf_b, out);
}